// Round 3
// baseline (195.141 us; speedup 1.0000x reference)
//
#include <hip/hip_runtime.h>

typedef short short8 __attribute__((ext_vector_type(8)));
typedef float f32x4 __attribute__((ext_vector_type(4)));

#define BN_EPS 1e-5f
#define CUT_THRESH 1e-3f

// ws layout (bytes):
//   [0, 4096)        amax (32*32 uint, zeroed per call)
//   [4096, 22528)    wbf  (9216 bf16, [kk][co][ci] with ci-octet ^ ((co>>1)&3) swizzle)
//   [22528, 22784)   coef (64 f32: scl[0:32], sft[32:64])
//   [23040, +77.1MB) xbf  (padded swizzled bf16 NHWC: [b][194][194][32])
#define WS_WBF   4096
#define WS_COEF  22528
#define WS_XBF   23040
#define XBF_PIX  37636                                  // 194*194
#define XBF_BYTES ((size_t)32 * XBF_PIX * 64)           // 77,074,432

__device__ __forceinline__ unsigned short f2bf(float f) {
  unsigned u = __float_as_uint(f);
  u += 0x7FFFu + ((u >> 16) & 1u);  // RNE
  return (unsigned short)(u >> 16);
}

__device__ __forceinline__ void gload_lds16(const void* g, void* l) {
  __builtin_amdgcn_global_load_lds(
      (const __attribute__((address_space(1))) unsigned int*)g,
      (__attribute__((address_space(3))) unsigned int*)l, 16, 0, 0);
}

// One-time weight conversion + BN coefficient fusion.
__global__ void prep_kernel(const float* __restrict__ wgt,
                            const float* __restrict__ bias,
                            const float* __restrict__ gamma,
                            const float* __restrict__ beta,
                            const float* __restrict__ rmean,
                            const float* __restrict__ rvar,
                            unsigned short* __restrict__ wbf,
                            float* __restrict__ coef) {
  int tid = blockIdx.x * 256 + threadIdx.x;
  if (tid < 9216) {
    int co = tid / 288;  // wgt is OIHW
    int rem = tid - co * 288;
    int ci = rem / 9;
    int kk = rem - ci * 9;
    int oct = ((ci >> 3) ^ ((co >> 1) & 3)) << 3;
    wbf[(kk * 32 + co) * 32 + oct + (ci & 7)] = f2bf(wgt[tid]);
  }
  if (tid < 32) {
    float s = gamma[tid] * rsqrtf(rvar[tid] + BN_EPS);
    coef[tid] = s;
    coef[32 + tid] = (bias[tid] - rmean[tid]) * s + beta[tid];
  }
}

// NCHW fp32 -> padded swizzled NHWC bf16. One thread per padded pixel (hp,wp).
// Slot g of a pixel holds ci-octet (g ^ ((wp>>1)&3)); zero halo at hp/wp in {0,193}.
__global__ __launch_bounds__(256) void cast_kernel(const float* __restrict__ x,
                                                   unsigned short* __restrict__ xbf) {
  int blk = blockIdx.x;
  int b = blk / 148;
  int p = (blk - b * 148) * 256 + threadIdx.x;
  if (p >= XBF_PIX) return;
  int hp = p / 194;
  int wp = p - hp * 194;
  unsigned short* dst = xbf + ((size_t)b * XBF_PIX + p) * 32;
  if (hp == 0 || hp == 193 || wp == 0 || wp == 193) {
    short8 z = {0, 0, 0, 0, 0, 0, 0, 0};
#pragma unroll
    for (int g = 0; g < 4; ++g) *reinterpret_cast<short8*>(dst + g * 8) = z;
    return;
  }
  const float* src = x + (size_t)b * (32 * 36864) + (hp - 1) * 192 + (wp - 1);
  int s = (wp >> 1) & 3;
#pragma unroll
  for (int g = 0; g < 4; ++g) {
    int cb = (g ^ s) << 3;
    short8 v;
#pragma unroll
    for (int e = 0; e < 8; ++e)
      v[e] = (short)f2bf(src[(size_t)(cb + e) * 36864]);  // 32 independent loads total
    *reinterpret_cast<short8*>(dst + g * 8) = v;
  }
}

// Implicit-GEMM conv 3x3 + BN + ReLU + plane-absmax. Staging = pure DMA.
// Block: 256 thr = 4 waves; tile = 8 rows x 32 cols x 32 Cout, one batch.
__global__ __launch_bounds__(256, 4) void conv_dma_kernel(
    const unsigned short* __restrict__ xbf,
    const unsigned short* __restrict__ wbf,
    const float* __restrict__ coef,
    float* __restrict__ out, unsigned int* __restrict__ amax) {
  __shared__ unsigned short lx[10 * 34 * 32];  // 21760 B, chunk-linear copy of xbf tile
  __shared__ unsigned short lw[9 * 32 * 32];   // 18432 B

  int bid = blockIdx.x;
  int orig = (bid & 7) * 576 + (bid >> 3);  // XCD-bijective: 4608 = 8*576
  int b = orig / 144;
  int t = orig - b * 144;
  int tr = t / 6, tc = t - tr * 6;
  int r0 = tr * 8, c0 = tc * 32;
  int tid = threadIdx.x;

  // weights: 1152 x 16B DMA chunks
  {
    const short8* wsrc = reinterpret_cast<const short8*>(wbf);
    short8* wdst = reinterpret_cast<short8*>(lw);
#pragma unroll
    for (int r = 0; r < 4; ++r) gload_lds16(wsrc + r * 256 + tid, wdst + r * 256 + tid);
    if (tid < 128) gload_lds16(wsrc + 1024 + tid, wdst + 1024 + tid);
  }
  // x tile: 10 rows x 136 chunks = 1360 x 16B DMA chunks (halo pre-materialized)
  {
    const short8* xsrc = reinterpret_cast<const short8*>(
        xbf + ((size_t)b * XBF_PIX + (size_t)r0 * 194 + c0) * 32);
    short8* xdst = reinterpret_cast<short8*>(lx);
#pragma unroll
    for (int r = 0; r < 5; ++r) {
      int idx = r * 256 + tid;
      int row = idx / 136;  // const divisor -> mul_hi
      int i = idx - row * 136;
      gload_lds16(xsrc + row * 776 + i, xdst + idx);
    }
    if (tid < 80) {
      int idx = 1280 + tid;
      int row = idx / 136;
      int i = idx - row * 136;
      gload_lds16(xsrc + row * 776 + i, xdst + idx);
    }
  }

  int lane = tid & 63;
  int wv = tid >> 6;  // wave -> rows 2wv, 2wv+1 of the 8-row tile
  int l15 = lane & 15;
  int lg = lane >> 4;

  f32x4 scl[2], sft[2];
#pragma unroll
  for (int m = 0; m < 2; ++m) {
    scl[m] = *reinterpret_cast<const f32x4*>(coef + m * 16 + lg * 4);
    sft[m] = *reinterpret_cast<const f32x4*>(coef + 32 + m * 16 + lg * 4);
  }

  __syncthreads();

  int aswz = (lg ^ ((l15 >> 1) & 3)) << 3;
  short8 Af[9][2];
#pragma unroll
  for (int s = 0; s < 9; ++s)
#pragma unroll
    for (int m = 0; m < 2; ++m)
      Af[s][m] = *reinterpret_cast<const short8*>(
          &lw[(s * 32 + m * 16 + l15) * 32 + aswz]);

  f32x4 acc[2][4] = {};

#pragma unroll
  for (int s = 0; s < 9; ++s) {
    const int kh = s / 3, kw = s - kh * 3;
#pragma unroll
    for (int n = 0; n < 4; ++n) {
      int hl = 2 * wv + (n >> 1) + kh;
      int wl = ((n & 1) << 4) + l15 + kw;
      short8 Bf = *reinterpret_cast<const short8*>(
          &lx[(hl * 34 + wl) * 32 + ((lg ^ ((wl >> 1) & 3)) << 3)]);
      acc[0][n] = __builtin_amdgcn_mfma_f32_16x16x32_bf16(Af[s][0], Bf, acc[0][n], 0, 0, 0);
      acc[1][n] = __builtin_amdgcn_mfma_f32_16x16x32_bf16(Af[s][1], Bf, acc[1][n], 0, 0, 0);
    }
  }

  const int HW = 192 * 192;
  float* ob = out + b * 32 * HW;
  float pmax[2][4];
#pragma unroll
  for (int m = 0; m < 2; ++m)
#pragma unroll
    for (int j = 0; j < 4; ++j) pmax[m][j] = 0.f;

#pragma unroll
  for (int m = 0; m < 2; ++m)
#pragma unroll
    for (int n = 0; n < 4; ++n) {
      int gr = r0 + 2 * wv + (n >> 1);
      int gc = c0 + ((n & 1) << 4) + l15;
#pragma unroll
      for (int j = 0; j < 4; ++j) {
        int co = m * 16 + lg * 4 + j;  // D row = (lane>>4)*4 + reg (m89-verified)
        float v = fmaxf(acc[m][n][j] * scl[m][j] + sft[m][j], 0.f);
        ob[co * HW + gr * 192 + gc] = v;
        pmax[m][j] = fmaxf(pmax[m][j], v);
      }
    }

#pragma unroll
  for (int m = 0; m < 2; ++m)
#pragma unroll
    for (int j = 0; j < 4; ++j) {
      float v = pmax[m][j];
      v = fmaxf(v, __shfl_xor(v, 1, 16));
      v = fmaxf(v, __shfl_xor(v, 2, 16));
      v = fmaxf(v, __shfl_xor(v, 4, 16));
      v = fmaxf(v, __shfl_xor(v, 8, 16));
      if (l15 == 0)
        atomicMax(&amax[b * 32 + m * 16 + lg * 4 + j], __float_as_uint(v));
    }
}

// ---------------- fallback (round-2 path, used only if ws too small) ----------
__device__ __forceinline__ void stage_task(int id, const float* __restrict__ xb,
                                           int r0, int c0,
                                           unsigned short* __restrict__ lx) {
  int g = id & 3;
  int p = id >> 2;
  int h = p / 34;
  int w = p - h * 34;
  int gh = r0 - 1 + h, gw = c0 - 1 + w;
  bool ok = ((unsigned)gh < 192u) && ((unsigned)gw < 192u);
  int ghc = min(max(gh, 0), 191);
  int gwc = min(max(gw, 0), 191);
  const float* src = xb + (g * 8) * 36864 + ghc * 192 + gwc;
  short8 v;
#pragma unroll
  for (int j = 0; j < 8; ++j) {
    float f = src[j * 36864];
    f = ok ? f : 0.f;
    v[j] = (short)f2bf(f);
  }
  *reinterpret_cast<short8*>(&lx[p * 32 + ((g ^ ((w >> 1) & 3)) << 3)]) = v;
}

__global__ __launch_bounds__(256, 3) void conv_fallback_kernel(
    const float* __restrict__ x, const unsigned short* __restrict__ wbf,
    const float* __restrict__ coef, float* __restrict__ out,
    unsigned int* __restrict__ amax) {
  __shared__ unsigned short lx[10 * 34 * 32];
  __shared__ unsigned short lw[9 * 32 * 32];
  int bid = blockIdx.x;
  int orig = (bid & 7) * 576 + (bid >> 3);
  int b = orig / 144;
  int t = orig - b * 144;
  int tr = t / 6, tc = t - tr * 6;
  int r0 = tr * 8, c0 = tc * 32;
  int tid = threadIdx.x;
  {
    const short8* wsrc = reinterpret_cast<const short8*>(wbf);
    short8* wdst = reinterpret_cast<short8*>(lw);
#pragma unroll
    for (int r = 0; r < 4; ++r) gload_lds16(wsrc + r * 256 + tid, wdst + r * 256 + tid);
    if (tid < 128) gload_lds16(wsrc + 1024 + tid, wdst + 1024 + tid);
  }
  const float* xb = x + b * (32 * 192 * 192);
#pragma unroll
  for (int r = 0; r < 5; ++r) stage_task(r * 256 + tid, xb, r0, c0, lx);
  if (tid < 80) stage_task(1280 + tid, xb, r0, c0, lx);

  int lane = tid & 63;
  int wv = tid >> 6;
  int l15 = lane & 15;
  int lg = lane >> 4;
  f32x4 scl[2], sft[2];
#pragma unroll
  for (int m = 0; m < 2; ++m) {
    scl[m] = *reinterpret_cast<const f32x4*>(coef + m * 16 + lg * 4);
    sft[m] = *reinterpret_cast<const f32x4*>(coef + 32 + m * 16 + lg * 4);
  }
  __syncthreads();
  int aswz = (lg ^ ((l15 >> 1) & 3)) << 3;
  short8 Af[9][2];
#pragma unroll
  for (int s = 0; s < 9; ++s)
#pragma unroll
    for (int m = 0; m < 2; ++m)
      Af[s][m] = *reinterpret_cast<const short8*>(
          &lw[(s * 32 + m * 16 + l15) * 32 + aswz]);
  f32x4 acc[2][4] = {};
#pragma unroll
  for (int s = 0; s < 9; ++s) {
    const int kh = s / 3, kw = s - kh * 3;
#pragma unroll
    for (int n = 0; n < 4; ++n) {
      int hl = 2 * wv + (n >> 1) + kh;
      int wl = ((n & 1) << 4) + l15 + kw;
      short8 Bf = *reinterpret_cast<const short8*>(
          &lx[(hl * 34 + wl) * 32 + ((lg ^ ((wl >> 1) & 3)) << 3)]);
      acc[0][n] = __builtin_amdgcn_mfma_f32_16x16x32_bf16(Af[s][0], Bf, acc[0][n], 0, 0, 0);
      acc[1][n] = __builtin_amdgcn_mfma_f32_16x16x32_bf16(Af[s][1], Bf, acc[1][n], 0, 0, 0);
    }
  }
  const int HW = 192 * 192;
  float* ob = out + b * 32 * HW;
  float pmax[2][4];
#pragma unroll
  for (int m = 0; m < 2; ++m)
#pragma unroll
    for (int j = 0; j < 4; ++j) pmax[m][j] = 0.f;
#pragma unroll
  for (int m = 0; m < 2; ++m)
#pragma unroll
    for (int n = 0; n < 4; ++n) {
      int gr = r0 + 2 * wv + (n >> 1);
      int gc = c0 + ((n & 1) << 4) + l15;
#pragma unroll
      for (int j = 0; j < 4; ++j) {
        float v = fmaxf(acc[m][n][j] * scl[m][j] + sft[m][j], 0.f);
        ob[(m * 16 + lg * 4 + j) * HW + gr * 192 + gc] = v;
        pmax[m][j] = fmaxf(pmax[m][j], v);
      }
    }
#pragma unroll
  for (int m = 0; m < 2; ++m)
#pragma unroll
    for (int j = 0; j < 4; ++j) {
      float v = pmax[m][j];
      v = fmaxf(v, __shfl_xor(v, 1, 16));
      v = fmaxf(v, __shfl_xor(v, 2, 16));
      v = fmaxf(v, __shfl_xor(v, 4, 16));
      v = fmaxf(v, __shfl_xor(v, 8, 16));
      if (l15 == 0)
        atomicMax(&amax[b * 32 + m * 16 + lg * 4 + j], __float_as_uint(v));
    }
}

// Zero a (b,co) plane only if its absmax < CUT_THRESH.
__global__ void cut_kernel(float* __restrict__ out,
                           const unsigned int* __restrict__ amax) {
  int p = blockIdx.x;
  if (__uint_as_float(amax[p]) >= CUT_THRESH) return;
  float* base = out + p * 36864;
  for (int i = threadIdx.x; i < 36864; i += 256) base[i] = 0.f;
}

extern "C" void kernel_launch(void* const* d_in, const int* in_sizes, int n_in,
                              void* d_out, int out_size, void* d_ws, size_t ws_size,
                              hipStream_t stream) {
  const float* x     = (const float*)d_in[0];
  const float* wgt   = (const float*)d_in[1];
  const float* bias  = (const float*)d_in[2];
  const float* gamma = (const float*)d_in[3];
  const float* beta  = (const float*)d_in[4];
  const float* rmean = (const float*)d_in[5];
  const float* rvar  = (const float*)d_in[6];
  float* out = (float*)d_out;

  unsigned int*   amax = (unsigned int*)d_ws;
  unsigned short* wbf  = (unsigned short*)((char*)d_ws + WS_WBF);
  float*          coef = (float*)((char*)d_ws + WS_COEF);
  unsigned short* xbf  = (unsigned short*)((char*)d_ws + WS_XBF);

  hipMemsetAsync(amax, 0, 4096, stream);
  prep_kernel<<<36, 256, 0, stream>>>(wgt, bias, gamma, beta, rmean, rvar, wbf, coef);
  if (ws_size >= (size_t)WS_XBF + XBF_BYTES) {
    cast_kernel<<<148 * 32, 256, 0, stream>>>(x, xbf);
    conv_dma_kernel<<<4608, 256, 0, stream>>>(xbf, wbf, coef, out, amax);
  } else {
    conv_fallback_kernel<<<4608, 256, 0, stream>>>(x, wbf, coef, out, amax);
  }
  cut_kernel<<<1024, 256, 0, stream>>>(out, amax);
}

// Round 4
// 170.104 us; speedup vs baseline: 1.1472x; 1.1472x over previous
//
#include <hip/hip_runtime.h>

typedef short short8 __attribute__((ext_vector_type(8)));
typedef float f32x4 __attribute__((ext_vector_type(4)));

#define BN_EPS 1e-5f
#define CUT_THRESH 1e-3f

// ws layout (bytes):
//   [0, 18432)       wbf  (9216 bf16, [kk][co][ci] with ci-octet ^ ((co>>1)&3) swizzle)
//   [18432, 18688)   coef (64 f32: scl[0:32], sft[32:64])
//   [18688, +2.36MB) part (4608 tiles * 4 waves * 32 co f32 partial plane-maxes)
#define WS_COEF 18432
#define WS_PART 18688

__device__ __forceinline__ unsigned short f2bf(float f) {
  unsigned u = __float_as_uint(f);
  u += 0x7FFFu + ((u >> 16) & 1u);  // RNE
  return (unsigned short)(u >> 16);
}

// One-time weight conversion + BN coefficient fusion.
__global__ void prep_kernel(const float* __restrict__ wgt,
                            const float* __restrict__ bias,
                            const float* __restrict__ gamma,
                            const float* __restrict__ beta,
                            const float* __restrict__ rmean,
                            const float* __restrict__ rvar,
                            unsigned short* __restrict__ wbf,
                            float* __restrict__ coef) {
  int tid = blockIdx.x * 256 + threadIdx.x;
  if (tid < 9216) {
    int co = tid / 288;  // wgt is OIHW
    int rem = tid - co * 288;
    int ci = rem / 9;
    int kk = rem - ci * 9;
    int oct = ((ci >> 3) ^ ((co >> 1) & 3)) << 3;
    wbf[(kk * 32 + co) * 32 + oct + (ci & 7)] = f2bf(wgt[tid]);
  }
  if (tid < 32) {
    float s = gamma[tid] * rsqrtf(rvar[tid] + BN_EPS);
    coef[tid] = s;
    coef[32 + tid] = (bias[tid] - rmean[tid]) * s + beta[tid];
  }
}

// Stage one (pixel p, ci-octet g): 8 fp32 loads -> one swizzled ds_write_b128.
__device__ __forceinline__ void stage_task(int id, const float* __restrict__ xb,
                                           int r0, int c0,
                                           unsigned short* __restrict__ lx) {
  int g = id & 3;
  int p = id >> 2;  // 0..339 = h*34 + w
  int h = p / 34;
  int w = p - h * 34;
  int gh = r0 - 1 + h, gw = c0 - 1 + w;
  bool ok = ((unsigned)gh < 192u) && ((unsigned)gw < 192u);
  int ghc = min(max(gh, 0), 191);
  int gwc = min(max(gw, 0), 191);
  const float* src = xb + (g * 8) * 36864 + ghc * 192 + gwc;
  short8 v;
#pragma unroll
  for (int j = 0; j < 8; ++j) {
    float f = src[j * 36864];  // clamped addr always safe; 8 independent loads
    f = ok ? f : 0.f;
    v[j] = (short)f2bf(f);
  }
  *reinterpret_cast<short8*>(&lx[p * 32 + ((g ^ ((w >> 1) & 3)) << 3)]) = v;
}

// Implicit-GEMM conv 3x3 + BN + ReLU + per-wave plane-max partials (NO atomics).
// Block: 256 thr = 4 waves; tile = 8 rows x 32 cols x 32 Cout, one batch.
__global__ __launch_bounds__(256, 4) void conv_bn_relu_kernel(
    const float* __restrict__ x,
    const unsigned short* __restrict__ wbf,
    const float* __restrict__ coef,
    float* __restrict__ out,
    float* __restrict__ part) {
  __shared__ unsigned short lx[10 * 34 * 32];  // 21.76 KB only -> more blocks/CU

  int bid = blockIdx.x;
  int orig = (bid & 7) * 576 + (bid >> 3);  // XCD-bijective: 4608 = 8*576
  int b = orig / 144;
  int t = orig - b * 144;
  int tr = t / 6, tc = t - tr * 6;
  int r0 = tr * 8, c0 = tc * 32;
  int tid = threadIdx.x;

  int lane = tid & 63;
  int wv = tid >> 6;  // wave -> rows 2wv, 2wv+1 of the 8-row tile
  int l15 = lane & 15;
  int lg = lane >> 4;

  // ---- A fragments straight from L2-resident global wbf (no LDS, no barrier dep)
  int aswz = (lg ^ ((l15 >> 1) & 3)) << 3;
  short8 Af[9][2];
#pragma unroll
  for (int s = 0; s < 9; ++s)
#pragma unroll
    for (int m = 0; m < 2; ++m)
      Af[s][m] = *reinterpret_cast<const short8*>(
          &wbf[(s * 32 + m * 16 + l15) * 32 + aswz]);

  // ---- stage x: 1360 octet-tasks (in-kernel fp32->bf16 cvt, swizzled b128 writes)
  const float* xb = x + b * (32 * 192 * 192);
#pragma unroll
  for (int r = 0; r < 5; ++r) stage_task(r * 256 + tid, xb, r0, c0, lx);
  if (tid < 80) stage_task(1280 + tid, xb, r0, c0, lx);

  f32x4 scl[2], sft[2];
#pragma unroll
  for (int m = 0; m < 2; ++m) {
    scl[m] = *reinterpret_cast<const f32x4*>(coef + m * 16 + lg * 4);
    sft[m] = *reinterpret_cast<const f32x4*>(coef + 32 + m * 16 + lg * 4);
  }

  __syncthreads();

  f32x4 acc[2][4] = {};

#pragma unroll
  for (int s = 0; s < 9; ++s) {
    const int kh = s / 3, kw = s - kh * 3;
#pragma unroll
    for (int n = 0; n < 4; ++n) {
      int hl = 2 * wv + (n >> 1) + kh;
      int wl = ((n & 1) << 4) + l15 + kw;
      short8 Bf = *reinterpret_cast<const short8*>(
          &lx[(hl * 34 + wl) * 32 + ((lg ^ ((wl >> 1) & 3)) << 3)]);
      acc[0][n] = __builtin_amdgcn_mfma_f32_16x16x32_bf16(Af[s][0], Bf, acc[0][n], 0, 0, 0);
      acc[1][n] = __builtin_amdgcn_mfma_f32_16x16x32_bf16(Af[s][1], Bf, acc[1][n], 0, 0, 0);
    }
  }

  // ---- epilogue: BN + ReLU, store, per-plane max partials ----
  const int HW = 192 * 192;
  float* ob = out + b * 32 * HW;
  float pmax[2][4];
#pragma unroll
  for (int m = 0; m < 2; ++m)
#pragma unroll
    for (int j = 0; j < 4; ++j) pmax[m][j] = 0.f;

#pragma unroll
  for (int m = 0; m < 2; ++m)
#pragma unroll
    for (int n = 0; n < 4; ++n) {
      int gr = r0 + 2 * wv + (n >> 1);
      int gc = c0 + ((n & 1) << 4) + l15;
#pragma unroll
      for (int j = 0; j < 4; ++j) {
        int co = m * 16 + lg * 4 + j;  // D row = (lane>>4)*4 + reg (m89-verified)
        float v = fmaxf(acc[m][n][j] * scl[m][j] + sft[m][j], 0.f);
        ob[co * HW + gr * 192 + gc] = v;
        pmax[m][j] = fmaxf(pmax[m][j], v);
      }
    }

  // 16-lane reduce; l15==0 lanes write 8 partial maxes each -> unique slots, no atomics
#pragma unroll
  for (int m = 0; m < 2; ++m)
#pragma unroll
    for (int j = 0; j < 4; ++j) {
      float v = pmax[m][j];
      v = fmaxf(v, __shfl_xor(v, 1, 16));
      v = fmaxf(v, __shfl_xor(v, 2, 16));
      v = fmaxf(v, __shfl_xor(v, 4, 16));
      v = fmaxf(v, __shfl_xor(v, 8, 16));
      if (l15 == 0)
        part[(orig * 4 + wv) * 32 + m * 16 + lg * 4 + j] = v;
    }
}

// Per (b,co) plane: reduce 144 tiles x 4 waves of partials; zero plane if < thresh.
__global__ __launch_bounds__(256) void cut_kernel(float* __restrict__ out,
                                                  const float* __restrict__ part) {
  __shared__ float red[4];
  int p = blockIdx.x;        // b*32 + co
  int b = p >> 5, co = p & 31;
  const float* pp = part + (size_t)b * 576 * 32 + co;
  float m = 0.f;
  for (int i = threadIdx.x; i < 576; i += 256) m = fmaxf(m, pp[i * 32]);
#pragma unroll
  for (int k = 1; k < 64; k <<= 1) m = fmaxf(m, __shfl_xor(m, k, 64));
  int wv = threadIdx.x >> 6;
  if ((threadIdx.x & 63) == 0) red[wv] = m;
  __syncthreads();
  m = fmaxf(fmaxf(red[0], red[1]), fmaxf(red[2], red[3]));
  if (m >= CUT_THRESH) return;  // uniform branch; cut never fires on this data
  float* base = out + (size_t)p * 36864;
  for (int i = threadIdx.x; i < 36864; i += 256) base[i] = 0.f;
}

extern "C" void kernel_launch(void* const* d_in, const int* in_sizes, int n_in,
                              void* d_out, int out_size, void* d_ws, size_t ws_size,
                              hipStream_t stream) {
  const float* x     = (const float*)d_in[0];
  const float* wgt   = (const float*)d_in[1];
  const float* bias  = (const float*)d_in[2];
  const float* gamma = (const float*)d_in[3];
  const float* beta  = (const float*)d_in[4];
  const float* rmean = (const float*)d_in[5];
  const float* rvar  = (const float*)d_in[6];
  float* out = (float*)d_out;

  unsigned short* wbf  = (unsigned short*)d_ws;
  float*          coef = (float*)((char*)d_ws + WS_COEF);
  float*          part = (float*)((char*)d_ws + WS_PART);

  prep_kernel<<<36, 256, 0, stream>>>(wgt, bias, gamma, beta, rmean, rvar, wbf, coef);
  conv_bn_relu_kernel<<<4608, 256, 0, stream>>>(x, wbf, coef, out, part);
  cut_kernel<<<1024, 256, 0, stream>>>(out, part);
}

// Round 5
// 102.936 us; speedup vs baseline: 1.8957x; 1.6525x over previous
//
#include <hip/hip_runtime.h>

typedef short short8 __attribute__((ext_vector_type(8)));
typedef float f32x4 __attribute__((ext_vector_type(4)));

#define BN_EPS 1e-5f
#define CUT_THRESH 1e-3f

// ws layout (bytes):
//   [0, 18432)        wbf  (9216 bf16, [kk][co][ci] ci-octet ^ ((co>>1)&3) swizzle)
//   [18432, 18688)    coef (64 f32: scl[0:32], sft[32:64])
//   [18688, +589824)  part (1024 planes x 144 tiles f32 partial plane-maxes)
#define WS_COEF 18432
#define WS_PART 18688

__device__ __forceinline__ unsigned short f2bf(float f) {
  unsigned u = __float_as_uint(f);
  u += 0x7FFFu + ((u >> 16) & 1u);  // RNE (prep only; negligible cost there)
  return (unsigned short)(u >> 16);
}

__device__ __forceinline__ void gload_lds16(const void* g, void* l) {
  __builtin_amdgcn_global_load_lds(
      (const __attribute__((address_space(1))) unsigned int*)g,
      (__attribute__((address_space(3))) unsigned int*)l, 16, 0, 0);
}

// One-time weight conversion + BN coefficient fusion.
__global__ void prep_kernel(const float* __restrict__ wgt,
                            const float* __restrict__ bias,
                            const float* __restrict__ gamma,
                            const float* __restrict__ beta,
                            const float* __restrict__ rmean,
                            const float* __restrict__ rvar,
                            unsigned short* __restrict__ wbf,
                            float* __restrict__ coef) {
  int tid = blockIdx.x * 256 + threadIdx.x;
  if (tid < 9216) {
    int co = tid / 288;  // wgt is OIHW
    int rem = tid - co * 288;
    int ci = rem / 9;
    int kk = rem - ci * 9;
    int oct = ((ci >> 3) ^ ((co >> 1) & 3)) << 3;
    wbf[(kk * 32 + co) * 32 + oct + (ci & 7)] = f2bf(wgt[tid]);
  }
  if (tid < 32) {
    float s = gamma[tid] * rsqrtf(rvar[tid] + BN_EPS);
    coef[tid] = s;
    coef[32 + tid] = (bias[tid] - rmean[tid]) * s + beta[tid];
  }
}

// Implicit-GEMM conv 3x3 + BN + ReLU; tile 8x32 px x 32 co per 256-thr block.
// Staging: phase-1 issues ALL 48 x-loads (max MLP), phase-2 converts+ds_writes.
__global__ __launch_bounds__(256, 3) void conv_bn_relu_kernel(
    const float* __restrict__ x,
    const unsigned short* __restrict__ wbf,
    const float* __restrict__ coef,
    float* __restrict__ out,
    float* __restrict__ part) {
  __shared__ unsigned short lx[10 * 34 * 32];  // 21760 B
  __shared__ unsigned short lw[9 * 32 * 32];   // 18432 B
  __shared__ float red[4][32];                 // 512 B  (total 40704 B -> 4 blk/CU)

  int bid = blockIdx.x;
  int orig = (bid & 7) * 576 + (bid >> 3);  // XCD-bijective: 4608 = 8*576
  int b = orig / 144;
  int t = orig - b * 144;
  int tr = t / 6, tc = t - tr * 6;
  int r0 = tr * 8, c0 = tc * 32;
  int tid = threadIdx.x;

  // ---- weights: 1152 x 16B DMA chunks (issued first; drained by the barrier)
  {
    const short8* wsrc = reinterpret_cast<const short8*>(wbf);
    short8* wdst = reinterpret_cast<short8*>(lw);
#pragma unroll
    for (int r = 0; r < 4; ++r) gload_lds16(wsrc + r * 256 + tid, wdst + r * 256 + tid);
    if (tid < 128) gload_lds16(wsrc + 1024 + tid, wdst + 1024 + tid);
  }

  // ---- x staging: 1360 octet-tasks; every thread takes 6 slots (slot 5 wraps
  //      ids 1280..1359 with benign same-data duplication) ----
  const float* xb = x + b * (32 * 192 * 192);
  int m80 = tid;
  m80 = (m80 >= 160) ? m80 - 160 : m80;
  m80 = (m80 >= 80) ? m80 - 80 : m80;

  float fv[6][8];
  int lofs[6];
  int okm[6];
  // phase 1: compute addresses, issue all 48 independent loads
#pragma unroll
  for (int r = 0; r < 6; ++r) {
    int id = (r < 5) ? (r * 256 + tid) : (1280 + m80);
    int g = id & 3;
    int p = id >> 2;  // h*34 + w
    int h = p / 34;
    int w = p - h * 34;
    int gh = r0 - 1 + h, gw = c0 - 1 + w;
    okm[r] = (((unsigned)gh < 192u) && ((unsigned)gw < 192u)) ? -1 : 0;
    int ghc = min(max(gh, 0), 191);
    int gwc = min(max(gw, 0), 191);
    const float* src = xb + (g * 8) * 36864 + ghc * 192 + gwc;
#pragma unroll
    for (int j = 0; j < 8; ++j) fv[r][j] = src[j * 36864];  // 48 loads in flight
    lofs[r] = p * 32 + ((g ^ ((w >> 1) & 3)) << 3);
  }
  __builtin_amdgcn_sched_barrier(0);  // keep converts from sinking into load issue

  // phase 2: convert (round-half-up) + swizzled ds_write_b128
#pragma unroll
  for (int r = 0; r < 6; ++r) {
    unsigned pk[4];
#pragma unroll
    for (int q = 0; q < 4; ++q) {
      float f0 = okm[r] ? fv[r][2 * q] : 0.f;
      float f1 = okm[r] ? fv[r][2 * q + 1] : 0.f;
      unsigned a = __float_as_uint(f0) + 0x8000u;
      unsigned c = __float_as_uint(f1) + 0x8000u;
      pk[q] = (a >> 16) | (c & 0xffff0000u);
    }
    short8 v;
    *reinterpret_cast<unsigned*>(&v) = pk[0];
    *(reinterpret_cast<unsigned*>(&v) + 1) = pk[1];
    *(reinterpret_cast<unsigned*>(&v) + 2) = pk[2];
    *(reinterpret_cast<unsigned*>(&v) + 3) = pk[3];
    *reinterpret_cast<short8*>(&lx[lofs[r]]) = v;
  }

  int lane = tid & 63;
  int wv = tid >> 6;  // wave -> rows 2wv, 2wv+1
  int l15 = lane & 15;
  int lg = lane >> 4;

  f32x4 scl[2], sft[2];
#pragma unroll
  for (int m = 0; m < 2; ++m) {
    scl[m] = *reinterpret_cast<const f32x4*>(coef + m * 16 + lg * 4);
    sft[m] = *reinterpret_cast<const f32x4*>(coef + 32 + m * 16 + lg * 4);
  }

  __syncthreads();

  int aswz = (lg ^ ((l15 >> 1) & 3)) << 3;
  f32x4 acc[2][4] = {};

  // ---- MFMA loop: A-fragments read from LDS in-loop (register relief) ----
#pragma unroll
  for (int s = 0; s < 9; ++s) {
    const int kh = s / 3, kw = s - kh * 3;
    short8 A0 = *reinterpret_cast<const short8*>(&lw[(s * 32 + l15) * 32 + aswz]);
    short8 A1 = *reinterpret_cast<const short8*>(&lw[(s * 32 + 16 + l15) * 32 + aswz]);
#pragma unroll
    for (int n = 0; n < 4; ++n) {
      int hl = 2 * wv + (n >> 1) + kh;
      int wl = ((n & 1) << 4) + l15 + kw;
      short8 Bf = *reinterpret_cast<const short8*>(
          &lx[(hl * 34 + wl) * 32 + ((lg ^ ((wl >> 1) & 3)) << 3)]);
      acc[0][n] = __builtin_amdgcn_mfma_f32_16x16x32_bf16(A0, Bf, acc[0][n], 0, 0, 0);
      acc[1][n] = __builtin_amdgcn_mfma_f32_16x16x32_bf16(A1, Bf, acc[1][n], 0, 0, 0);
    }
  }

  // ---- epilogue: BN + ReLU, store, per-plane max partials (no atomics) ----
  const int HW = 192 * 192;
  float* ob = out + b * 32 * HW;
  float pmax[2][4];
#pragma unroll
  for (int m = 0; m < 2; ++m)
#pragma unroll
    for (int j = 0; j < 4; ++j) pmax[m][j] = 0.f;

#pragma unroll
  for (int m = 0; m < 2; ++m)
#pragma unroll
    for (int n = 0; n < 4; ++n) {
      int gr = r0 + 2 * wv + (n >> 1);
      int gc = c0 + ((n & 1) << 4) + l15;
#pragma unroll
      for (int j = 0; j < 4; ++j) {
        int co = m * 16 + lg * 4 + j;  // D row = (lane>>4)*4 + reg (m89-verified)
        float v = fmaxf(acc[m][n][j] * scl[m][j] + sft[m][j], 0.f);
        ob[co * HW + gr * 192 + gc] = v;
        pmax[m][j] = fmaxf(pmax[m][j], v);
      }
    }

  // 16-lane reduce -> red[wv][co] -> block reduce -> 32 contiguous part floats
#pragma unroll
  for (int m = 0; m < 2; ++m)
#pragma unroll
    for (int j = 0; j < 4; ++j) {
      float v = pmax[m][j];
      v = fmaxf(v, __shfl_xor(v, 1, 16));
      v = fmaxf(v, __shfl_xor(v, 2, 16));
      v = fmaxf(v, __shfl_xor(v, 4, 16));
      v = fmaxf(v, __shfl_xor(v, 8, 16));
      if (l15 == 0) red[wv][m * 16 + lg * 4 + j] = v;
    }
  __syncthreads();
  if (tid < 32) {
    float mx = fmaxf(fmaxf(red[0][tid], red[1][tid]),
                     fmaxf(red[2][tid], red[3][tid]));
    part[((size_t)b * 32 + tid) * 144 + t] = mx;
  }
}

// Per (b,co) plane: reduce 144 contiguous partials; zero plane if < thresh.
__global__ __launch_bounds__(256) void cut_kernel(float* __restrict__ out,
                                                  const float* __restrict__ part) {
  __shared__ float r4[4];
  int p = blockIdx.x;  // b*32 + co
  const float* pp = part + (size_t)p * 144;
  float m = 0.f;
  if (threadIdx.x < 144) m = pp[threadIdx.x];
#pragma unroll
  for (int k = 1; k < 64; k <<= 1) m = fmaxf(m, __shfl_xor(m, k, 64));
  if ((threadIdx.x & 63) == 0) r4[threadIdx.x >> 6] = m;
  __syncthreads();
  m = fmaxf(fmaxf(r4[0], r4[1]), fmaxf(r4[2], r4[3]));
  if (m >= CUT_THRESH) return;  // uniform; cut never fires on this data
  float* base = out + (size_t)p * 36864;
  for (int i = threadIdx.x; i < 36864; i += 256) base[i] = 0.f;
}

extern "C" void kernel_launch(void* const* d_in, const int* in_sizes, int n_in,
                              void* d_out, int out_size, void* d_ws, size_t ws_size,
                              hipStream_t stream) {
  const float* x     = (const float*)d_in[0];
  const float* wgt   = (const float*)d_in[1];
  const float* bias  = (const float*)d_in[2];
  const float* gamma = (const float*)d_in[3];
  const float* beta  = (const float*)d_in[4];
  const float* rmean = (const float*)d_in[5];
  const float* rvar  = (const float*)d_in[6];
  float* out = (float*)d_out;

  unsigned short* wbf  = (unsigned short*)d_ws;
  float*          coef = (float*)((char*)d_ws + WS_COEF);
  float*          part = (float*)((char*)d_ws + WS_PART);

  prep_kernel<<<36, 256, 0, stream>>>(wgt, bias, gamma, beta, rmean, rvar, wbf, coef);
  conv_bn_relu_kernel<<<4608, 256, 0, stream>>>(x, wbf, coef, out, part);
  cut_kernel<<<1024, 256, 0, stream>>>(out, part);
}